// Round 1
// baseline (80258.014 us; speedup 1.0000x reference)
//
#include <hip/hip_runtime.h>
#include <math.h>

#define BB 64
#define FF 64
#define HH 1024
#define GG 4096
#define LIN 256
#define LOUT 64
#define NEXO 16
#define NENDO 48

// workspace float offsets
#define OFF_H0A 0
#define OFF_H0B 65536
#define OFF_C0  131072
#define OFF_H1A 196608
#define OFF_H1B 262144
#define OFF_C1  327680
#define OFF_X   393216
#define OFF_SRCT 397312
#define OFF_EXOT 1445888
#define WS_FLOATS 1511424

__device__ __forceinline__ float sigf(float x) { return 1.0f / (1.0f + expf(-x)); }

// ---------------- prep: zero states, transpose src/exo, init decoder x ----------------
__global__ void prep_kernel(const float* __restrict__ src, const float* __restrict__ trg,
                            float* __restrict__ ws)
{
    const int total = 262144 + 1048576 + 65536 + 4096;
    for (int i = blockIdx.x * blockDim.x + threadIdx.x; i < total; i += gridDim.x * blockDim.x) {
        if (i < 262144) {
            int buf = i >> 16, r = i & 65535;
            int off = (buf == 0) ? OFF_H0A : (buf == 1) ? OFF_C0 : (buf == 2) ? OFF_H1A : OFF_C1;
            ws[off + r] = 0.0f;
        } else if (i < 262144 + 1048576) {
            int j = i - 262144;
            int t = j >> 12, rem = j & 4095, k = rem >> 6, b = rem & 63;
            // srcT[t][k][b] = src[b][t][k]
            ws[OFF_SRCT + j] = src[(b * LIN + t) * FF + k];
        } else if (i < 262144 + 1048576 + 65536) {
            int j = i - (262144 + 1048576);
            int t = j >> 10, e = (j >> 6) & 15, b = j & 63;
            // exoT[t][e][b] = trg[b][t][48+e]
            ws[OFF_EXOT + j] = trg[(b * LOUT + t) * FF + NENDO + e];
        } else {
            int j = i - (262144 + 1048576 + 65536);
            int k = j >> 6, b = j & 63;
            // x[k][b] = src[b][255][k]
            ws[OFF_X + j] = src[(b * LIN + (LIN - 1)) * FF + k];
        }
    }
}

// ---------------- one LSTM cell phase ----------------
// gates = xin @ Wih^T + hin @ Whh^T + bih + bhh ; c,h update.
// xin: [KX][B] k-major; hin/hout/cst: [H][B] k-major.
// grid 256 blocks x 256 thr; block owns 4 h-cols (16 gate cols); 4 waves split K.
template <int KX>
__global__ __launch_bounds__(256) void lstm_phase(
    const float* __restrict__ xin, const float* __restrict__ hin,
    float* __restrict__ hout, float* __restrict__ cst,
    const float* __restrict__ Wih, const float* __restrict__ Whh,
    const float* __restrict__ bih, const float* __restrict__ bhh)
{
    const int tid = threadIdx.x;
    const int lane = tid & 63;
    const int w = __builtin_amdgcn_readfirstlane(tid >> 6); // K-slice id, wave-uniform
    const int hbase = blockIdx.x * 4;

    float acc[16];
#pragma unroll
    for (int i = 0; i < 16; i++) acc[i] = 0.0f;

    // x part (KX columns)
    {
        const int ks = (KX / 4) * w, ke = ks + (KX / 4);
#pragma unroll 4
        for (int k = ks; k < ke; k++) {
            float v = xin[k * 64 + lane];
#pragma unroll
            for (int q = 0; q < 4; q++)
#pragma unroll
                for (int c = 0; c < 4; c++)
                    acc[q * 4 + c] = fmaf(v, Wih[(q * HH + hbase + c) * KX + k], acc[q * 4 + c]);
        }
    }
    // h part (1024 columns)
    {
        const int ks = 256 * w, ke = ks + 256;
#pragma unroll 4
        for (int k = ks; k < ke; k++) {
            float v = hin[k * 64 + lane];
#pragma unroll
            for (int q = 0; q < 4; q++)
#pragma unroll
                for (int c = 0; c < 4; c++)
                    acc[q * 4 + c] = fmaf(v, Whh[(q * HH + hbase + c) * HH + k], acc[q * 4 + c]);
        }
    }

    __shared__ float red[4][16][64];
#pragma unroll
    for (int i = 0; i < 16; i++) red[w][i][lane] = acc[i];
    __syncthreads();

    {
        const int c = tid >> 6; // 0..3 h-col within block
        const int hcol = hbase + c;
        float g[4];
#pragma unroll
        for (int q = 0; q < 4; q++) {
            int j = q * HH + hcol;
            float s = bih[j] + bhh[j];
#pragma unroll
            for (int ww = 0; ww < 4; ww++) s += red[ww][q * 4 + c][lane];
            g[q] = s;
        }
        float ig = sigf(g[0]);
        float fg = sigf(g[1]);
        float gg = tanhf(g[2]);
        float og = sigf(g[3]);
        int idx = hcol * 64 + lane;
        float cv = fg * cst[idx] + ig * gg;
        cst[idx] = cv;
        hout[idx] = og * tanhf(cv);
    }
}

// ---------------- decoder fc + next-x assembly ----------------
// blocks 0..47: pred[n] ; blocks 48..63: copy exo into x
__global__ __launch_bounds__(256) void fc_kernel(
    const float* __restrict__ h1, const float* __restrict__ fcW,
    const float* __restrict__ fcb, const float* __restrict__ exoT_t,
    float* __restrict__ xbuf, float* __restrict__ out, int t)
{
    const int tid = threadIdx.x, lane = tid & 63;
    const int w = __builtin_amdgcn_readfirstlane(tid >> 6);
    const int blk = blockIdx.x;
    if (blk < NENDO) {
        float acc = 0.0f;
        const int ks = 256 * w, ke = ks + 256;
#pragma unroll 4
        for (int k = ks; k < ke; k++)
            acc = fmaf(h1[k * 64 + lane], fcW[blk * HH + k], acc);
        __shared__ float red[4][64];
        red[w][lane] = acc;
        __syncthreads();
        if (tid < 64) {
            float s = fcb[blk] + red[0][lane] + red[1][lane] + red[2][lane] + red[3][lane];
            xbuf[blk * 64 + lane] = s;
            out[lane * (LOUT * NENDO) + t * NENDO + blk] = s;
        }
    } else {
        int e = blk - NENDO;
        if (tid < 64) xbuf[(NENDO + e) * 64 + lane] = exoT_t[e * 64 + lane];
    }
}

extern "C" void kernel_launch(void* const* d_in, const int* in_sizes, int n_in,
                              void* d_out, int out_size, void* d_ws, size_t ws_size,
                              hipStream_t stream)
{
    const float* src = (const float*)d_in[0];
    const float* trg = (const float*)d_in[1];
    const float* eWih0 = (const float*)d_in[2];
    const float* eWhh0 = (const float*)d_in[3];
    const float* ebih0 = (const float*)d_in[4];
    const float* ebhh0 = (const float*)d_in[5];
    const float* eWih1 = (const float*)d_in[6];
    const float* eWhh1 = (const float*)d_in[7];
    const float* ebih1 = (const float*)d_in[8];
    const float* ebhh1 = (const float*)d_in[9];
    const float* dWih0 = (const float*)d_in[10];
    const float* dWhh0 = (const float*)d_in[11];
    const float* dbih0 = (const float*)d_in[12];
    const float* dbhh0 = (const float*)d_in[13];
    const float* dWih1 = (const float*)d_in[14];
    const float* dWhh1 = (const float*)d_in[15];
    const float* dbih1 = (const float*)d_in[16];
    const float* dbhh1 = (const float*)d_in[17];
    const float* fcW = (const float*)d_in[18];
    const float* fcb = (const float*)d_in[19];

    float* ws = (float*)d_ws;
    float* out = (float*)d_out;

    float* h0a = ws + OFF_H0A;
    float* h0b = ws + OFF_H0B;
    float* c0 = ws + OFF_C0;
    float* h1a = ws + OFF_H1A;
    float* h1b = ws + OFF_H1B;
    float* c1 = ws + OFF_C1;
    float* xbuf = ws + OFF_X;
    float* srcT = ws + OFF_SRCT;
    float* exoT = ws + OFF_EXOT;

    prep_kernel<<<512, 256, 0, stream>>>(src, trg, ws);

    float* h0in = h0a; float* h0out = h0b;
    float* h1in = h1a; float* h1out = h1b;

    // encoder: 256 steps
    for (int t = 0; t < LIN; t++) {
        lstm_phase<FF><<<256, 256, 0, stream>>>(srcT + t * 4096, h0in, h0out, c0,
                                                eWih0, eWhh0, ebih0, ebhh0);
        lstm_phase<HH><<<256, 256, 0, stream>>>(h0out, h1in, h1out, c1,
                                                eWih1, eWhh1, ebih1, ebhh1);
        float* tmp;
        tmp = h0in; h0in = h0out; h0out = tmp;
        tmp = h1in; h1in = h1out; h1out = tmp;
    }

    // decoder: 64 steps
    for (int t = 0; t < LOUT; t++) {
        lstm_phase<FF><<<256, 256, 0, stream>>>(xbuf, h0in, h0out, c0,
                                                dWih0, dWhh0, dbih0, dbhh0);
        lstm_phase<HH><<<256, 256, 0, stream>>>(h0out, h1in, h1out, c1,
                                                dWih1, dWhh1, dbih1, dbhh1);
        fc_kernel<<<64, 256, 0, stream>>>(h1out, fcW, fcb, exoT + t * 1024,
                                          xbuf, out, t);
        float* tmp;
        tmp = h0in; h0in = h0out; h0out = tmp;
        tmp = h1in; h1in = h1out; h1out = tmp;
    }
}

// Round 2
// 34162.704 us; speedup vs baseline: 2.3493x; 2.3493x over previous
//
#include <hip/hip_runtime.h>
#include <math.h>

#define LIN 256
#define LOUT 64
#define NENDO 48

typedef __attribute__((ext_vector_type(8))) short short8;
typedef __attribute__((ext_vector_type(4))) float f32x4;

// ---------------- ws layout (bytes) ----------------
constexpr size_t O_H0THI_A = 0;
constexpr size_t O_H0TLO_A = O_H0THI_A + 131072;
constexpr size_t O_H0THI_B = O_H0TLO_A + 131072;
constexpr size_t O_H0TLO_B = O_H0THI_B + 131072;
constexpr size_t O_H1THI_A = O_H0TLO_B + 131072;
constexpr size_t O_H1TLO_A = O_H1THI_A + 131072;
constexpr size_t O_H1THI_B = O_H1TLO_A + 131072;
constexpr size_t O_H1TLO_B = O_H1THI_B + 131072;
constexpr size_t O_C0   = O_H1TLO_B + 131072;   // fp32 [1024][64]
constexpr size_t O_C1   = O_C0 + 262144;
constexpr size_t O_H0KM = O_C1 + 262144;        // fp32 [1024][64] (unused sink)
constexpr size_t O_H1KM = O_H0KM + 262144;      // fp32 [1024][64] for fc
constexpr size_t O_XBHI = O_H1KM + 262144;      // [64][64] ushort
constexpr size_t O_XBLO = O_XBHI + 8192;
constexpr size_t O_BIAS = O_XBLO + 8192;        // 4 * [1024][4] fp32 packed
constexpr size_t O_SXHI = O_BIAS + 65536;       // [256][64][64] ushort
constexpr size_t O_SXLO = O_SXHI + 2097152;
constexpr size_t O_EXHI = O_SXLO + 2097152;     // [64][64][16] ushort
constexpr size_t O_EXLO = O_EXHI + 131072;
constexpr size_t O_EW0XHI = O_EXLO + 131072;    // [4096][64]
constexpr size_t O_EW0XLO = O_EW0XHI + 524288;
constexpr size_t O_EW0HHI = O_EW0XLO + 524288;  // [4096][1024]
constexpr size_t O_EW0HLO = O_EW0HHI + 8388608;
constexpr size_t O_EW1XHI = O_EW0HLO + 8388608;
constexpr size_t O_EW1XLO = O_EW1XHI + 8388608;
constexpr size_t O_EW1HHI = O_EW1XLO + 8388608;
constexpr size_t O_EW1HLO = O_EW1HHI + 8388608;
constexpr size_t O_DW0XHI = O_EW1HLO + 8388608;
constexpr size_t O_DW0XLO = O_DW0XHI + 524288;
constexpr size_t O_DW0HHI = O_DW0XLO + 524288;
constexpr size_t O_DW0HLO = O_DW0HHI + 8388608;
constexpr size_t O_DW1XHI = O_DW0HLO + 8388608;
constexpr size_t O_DW1XLO = O_DW1XHI + 8388608;
constexpr size_t O_DW1HHI = O_DW1XLO + 8388608;
constexpr size_t O_DW1HLO = O_DW1HHI + 8388608;
// total ~109 MB

__device__ __forceinline__ unsigned short f2bh(float x) {
    unsigned int u = __float_as_uint(x);
    unsigned int r = (u + 0x7fffu + ((u >> 16) & 1u)) >> 16;
    return (unsigned short)r;
}
__device__ __forceinline__ float bh2f(unsigned short h) {
    return __uint_as_float(((unsigned int)h) << 16);
}
__device__ __forceinline__ float sigf(float x) { return 1.0f / (1.0f + expf(-x)); }

// ---------------- weight pack: fp32 [4096][K] (row = gate*1024+hcol) -> hi/lo bf16, row p = hcol*4+gate
__global__ void pack_w_kernel(const float* __restrict__ W, unsigned short* __restrict__ hi,
                              unsigned short* __restrict__ lo, int K, int logK)
{
    int n = 4096 * K;
    for (int i = blockIdx.x * blockDim.x + threadIdx.x; i < n; i += gridDim.x * blockDim.x) {
        int pr = i >> logK, k = i & (K - 1);
        int hcol = pr >> 2, gate = pr & 3;
        float v = W[((gate << 10) + hcol) * K + k];
        unsigned short h = f2bh(v);
        hi[i] = h;
        lo[i] = f2bh(v - bh2f(h));
    }
}

__global__ void pack_bias_kernel(const float* a0, const float* b0, const float* a1, const float* b1,
                                 const float* a2, const float* b2, const float* a3, const float* b3,
                                 float* d0, float* d1, float* d2, float* d3)
{
    int i = blockIdx.x * blockDim.x + threadIdx.x;
    if (i >= 4096) return;
    int hcol = i >> 2, gate = i & 3, s = (gate << 10) + hcol;
    d0[i] = a0[s] + b0[s];
    d1[i] = a1[s] + b1[s];
    d2[i] = a2[s] + b2[s];
    d3[i] = a3[s] + b3[s];
}

// ---------------- misc prep: zero states, split src/exo/x0 ----------------
__global__ void prep_misc(const float* __restrict__ src, const float* __restrict__ trg,
                          unsigned short* h0ahi, unsigned short* h0alo,
                          unsigned short* h1ahi, unsigned short* h1alo,
                          float* c0, float* c1,
                          unsigned short* sxhi, unsigned short* sxlo,
                          unsigned short* exhi, unsigned short* exlo,
                          unsigned short* xbhi, unsigned short* xblo)
{
    const int TOT = 262144 + 131072 + 1048576 + 65536 + 4096;
    for (int i = blockIdx.x * blockDim.x + threadIdx.x; i < TOT; i += gridDim.x * blockDim.x) {
        if (i < 262144) {
            int a = i >> 16, r = i & 65535;
            unsigned short* p = (a == 0) ? h0ahi : (a == 1) ? h0alo : (a == 2) ? h1ahi : h1alo;
            p[r] = 0;
        } else if (i < 262144 + 131072) {
            int j = i - 262144;
            if (j < 65536) c0[j] = 0.0f; else c1[j - 65536] = 0.0f;
        } else if (i < 262144 + 131072 + 1048576) {
            int j = i - (262144 + 131072);
            int t = j >> 12, rem = j & 4095, b = rem >> 6, k = rem & 63;
            float v = src[(b * LIN + t) * 64 + k];
            unsigned short h = f2bh(v);
            sxhi[j] = h; sxlo[j] = f2bh(v - bh2f(h));
        } else if (i < 262144 + 131072 + 1048576 + 65536) {
            int j = i - (262144 + 131072 + 1048576);
            int t = j >> 10, rem = j & 1023, b = rem >> 4, e = rem & 15;
            float v = trg[(b * LOUT + t) * 64 + NENDO + e];
            unsigned short h = f2bh(v);
            exhi[j] = h; exlo[j] = f2bh(v - bh2f(h));
        } else {
            int j = i - (262144 + 131072 + 1048576 + 65536);
            int b = j >> 6, k = j & 63;
            float v = src[(b * LIN + (LIN - 1)) * 64 + k];
            unsigned short h = f2bh(v);
            xbhi[j] = h; xblo[j] = f2bh(v - bh2f(h));
        }
    }
}

// ---------------- LSTM phase: MFMA bf16 split-2 ----------------
// grid 64 blocks x 1024 threads. Block g: packed gate-rows [64g,64g+64) = hcols [16g,16g+16), all 64 batch, full K.
// 16 waves = 4 row-tiles x 4 batch-tiles. B (states) staged via XOR-swizzled LDS; A (weights) direct global.
// x-part: XC chunks of XS; h-part: 8 chunks of 128.
template <int XC, int XS, int KXS>
__global__ __launch_bounds__(1024) void lstm_phase_mfma(
    const unsigned short* __restrict__ xhi, const unsigned short* __restrict__ xlo,   // [64][KXS]
    const unsigned short* __restrict__ hhi, const unsigned short* __restrict__ hlo,   // [64][1024]
    const unsigned short* __restrict__ Wxhi, const unsigned short* __restrict__ Wxlo, // [4096][KXS]
    const unsigned short* __restrict__ Whhi, const unsigned short* __restrict__ Whlo, // [4096][1024]
    const float* __restrict__ biasP,                                                   // [1024][4]
    float* __restrict__ cst,                                                           // [1024][64]
    unsigned short* __restrict__ houthi, unsigned short* __restrict__ houtlo,          // [64][1024]
    float* __restrict__ hkmaj)                                                         // [1024][64]
{
    constexpr int NCH = XC + 8;
    __shared__ unsigned short lds[2][2][64 * 128];

    const int tid = threadIdx.x;
    const int l = tid & 63;
    const int w = tid >> 6;
    const int rt = w >> 2, nt = w & 3;
    const int g = blockIdx.x;
    const int l15 = l & 15, lq = l >> 4;

    const int p = 64 * g + 16 * rt + l15;   // A row (packed)
    const int brow = nt * 16 + l15;         // B col (batch)

    f32x4 acc = {0.f, 0.f, 0.f, 0.f};

    // staging coordinates for both chunk sizes
    const int sb128 = tid >> 4, kk128 = (tid & 15) * 8;
    const int sb64 = tid >> 3, kk64 = (tid & 7) * 8;

    auto do_load = [&](int c, short8& vh, short8& vl) {
        if (c < XC) {
            if (XS == 128 || tid < 512) {
                int sb = (XS == 128) ? sb128 : sb64;
                int kk = (XS == 128) ? kk128 : kk64;
                int off = sb * KXS + c * XS + kk;
                vh = *(const short8*)(xhi + off);
                vl = *(const short8*)(xlo + off);
            }
        } else {
            int off = sb128 * 1024 + (c - XC) * 128 + kk128;
            vh = *(const short8*)(hhi + off);
            vl = *(const short8*)(hlo + off);
        }
    };
    auto do_write = [&](int c, int buf, short8 vh, short8 vl) {
        int S = (c < XC) ? XS : 128;
        int sb, kk; bool act = true;
        if (S == 128) { sb = sb128; kk = kk128; }
        else { sb = sb64; kk = kk64; act = tid < 512; }
        if (act) {
            int uidx = (sb * S + kk) ^ ((sb & 7) << 3);
            *(short8*)&lds[buf][0][uidx] = vh;
            *(short8*)&lds[buf][1][uidx] = vl;
        }
    };
    auto compute = [&](int c, int buf) {
        const unsigned short *wh_, *wl_; int ks, kb, S;
        if (c < XC) { wh_ = Wxhi; wl_ = Wxlo; ks = KXS; kb = c * XS; S = XS; }
        else { wh_ = Whhi; wl_ = Whlo; ks = 1024; kb = (c - XC) * 128; S = 128; }
        const unsigned short* wah = wh_ + (size_t)p * ks + kb + lq * 8;
        const unsigned short* wal = wl_ + (size_t)p * ks + kb + lq * 8;
        const int nst = S >> 5;
#pragma unroll 4
        for (int s = 0; s < nst; s++) {
            short8 ah = *(const short8*)(wah + s * 32);
            short8 al = *(const short8*)(wal + s * 32);
            int uidx = (brow * S + s * 32 + lq * 8) ^ ((brow & 7) << 3);
            short8 bh = *(const short8*)&lds[buf][0][uidx];
            short8 bl = *(const short8*)&lds[buf][1][uidx];
            acc = __builtin_amdgcn_mfma_f32_16x16x32_bf16(ah, bh, acc, 0, 0, 0);
            acc = __builtin_amdgcn_mfma_f32_16x16x32_bf16(ah, bl, acc, 0, 0, 0);
            acc = __builtin_amdgcn_mfma_f32_16x16x32_bf16(al, bh, acc, 0, 0, 0);
        }
    };

    short8 vh, vl;
    do_load(0, vh, vl);
    do_write(0, 0, vh, vl);
    __syncthreads();
    for (int c = 0; c < NCH; c++) {
        short8 nh, nl;
        if (c + 1 < NCH) do_load(c + 1, nh, nl);      // issue early (T14)
        compute(c, c & 1);
        if (c + 1 < NCH) do_write(c + 1, (c + 1) & 1, nh, nl);
        __syncthreads();
    }

    // ---- epilogue: lane holds gates i,f,g,o (acc[0..3]) for (hcol, b) ----
    const int hcol = 16 * g + 4 * rt + lq;
    const int b = brow;
    f32x4 bias = *(const f32x4*)&biasP[hcol * 4];
    float ig = sigf(acc[0] + bias[0]);
    float fg = sigf(acc[1] + bias[1]);
    float gv = tanhf(acc[2] + bias[2]);
    float og = sigf(acc[3] + bias[3]);
    int cidx = hcol * 64 + b;
    float cv = fg * cst[cidx] + ig * gv;
    cst[cidx] = cv;
    float hv = og * tanhf(cv);
    hkmaj[cidx] = hv;
    unsigned short hh = f2bh(hv);
    houthi[b * 1024 + hcol] = hh;
    houtlo[b * 1024 + hcol] = f2bh(hv - bh2f(hh));
}

// ---------------- decoder fc + next-x assembly ----------------
__global__ __launch_bounds__(256) void fc_kernel(
    const float* __restrict__ h1, const float* __restrict__ fcW, const float* __restrict__ fcb,
    const unsigned short* __restrict__ exhi, const unsigned short* __restrict__ exlo,
    unsigned short* __restrict__ xbhi, unsigned short* __restrict__ xblo,
    float* __restrict__ out, int t)
{
    const int tid = threadIdx.x, lane = tid & 63;
    const int w = __builtin_amdgcn_readfirstlane(tid >> 6);
    const int blk = blockIdx.x;
    if (blk < NENDO) {
        float acc = 0.0f;
        const int ks = 256 * w, ke = ks + 256;
#pragma unroll 4
        for (int k = ks; k < ke; k++)
            acc = fmaf(h1[k * 64 + lane], fcW[blk * 1024 + k], acc);
        __shared__ float red[4][64];
        red[w][lane] = acc;
        __syncthreads();
        if (tid < 64) {
            float s = fcb[blk] + red[0][lane] + red[1][lane] + red[2][lane] + red[3][lane];
            out[lane * (LOUT * NENDO) + t * NENDO + blk] = s;
            unsigned short h = f2bh(s);
            xbhi[lane * 64 + blk] = h;
            xblo[lane * 64 + blk] = f2bh(s - bh2f(h));
        }
    } else {
        int e = blk - NENDO;
        if (tid < 64) {
            int si = t * 1024 + lane * 16 + e;
            xbhi[lane * 64 + NENDO + e] = exhi[si];
            xblo[lane * 64 + NENDO + e] = exlo[si];
        }
    }
}

extern "C" void kernel_launch(void* const* d_in, const int* in_sizes, int n_in,
                              void* d_out, int out_size, void* d_ws, size_t ws_size,
                              hipStream_t stream)
{
    const float* src = (const float*)d_in[0];
    const float* trg = (const float*)d_in[1];
    const float* eWih0 = (const float*)d_in[2];
    const float* eWhh0 = (const float*)d_in[3];
    const float* ebih0 = (const float*)d_in[4];
    const float* ebhh0 = (const float*)d_in[5];
    const float* eWih1 = (const float*)d_in[6];
    const float* eWhh1 = (const float*)d_in[7];
    const float* ebih1 = (const float*)d_in[8];
    const float* ebhh1 = (const float*)d_in[9];
    const float* dWih0 = (const float*)d_in[10];
    const float* dWhh0 = (const float*)d_in[11];
    const float* dbih0 = (const float*)d_in[12];
    const float* dbhh0 = (const float*)d_in[13];
    const float* dWih1 = (const float*)d_in[14];
    const float* dWhh1 = (const float*)d_in[15];
    const float* dbih1 = (const float*)d_in[16];
    const float* dbhh1 = (const float*)d_in[17];
    const float* fcW = (const float*)d_in[18];
    const float* fcb = (const float*)d_in[19];

    char* wsb = (char*)d_ws;
    float* out = (float*)d_out;
    auto U = [&](size_t o) { return (unsigned short*)(wsb + o); };
    auto F = [&](size_t o) { return (float*)(wsb + o); };

    // ---- prep ----
    pack_w_kernel<<<1024, 256, 0, stream>>>(eWih0, U(O_EW0XHI), U(O_EW0XLO), 64, 6);
    pack_w_kernel<<<4096, 256, 0, stream>>>(eWhh0, U(O_EW0HHI), U(O_EW0HLO), 1024, 10);
    pack_w_kernel<<<4096, 256, 0, stream>>>(eWih1, U(O_EW1XHI), U(O_EW1XLO), 1024, 10);
    pack_w_kernel<<<4096, 256, 0, stream>>>(eWhh1, U(O_EW1HHI), U(O_EW1HLO), 1024, 10);
    pack_w_kernel<<<1024, 256, 0, stream>>>(dWih0, U(O_DW0XHI), U(O_DW0XLO), 64, 6);
    pack_w_kernel<<<4096, 256, 0, stream>>>(dWhh0, U(O_DW0HHI), U(O_DW0HLO), 1024, 10);
    pack_w_kernel<<<4096, 256, 0, stream>>>(dWih1, U(O_DW1XHI), U(O_DW1XLO), 1024, 10);
    pack_w_kernel<<<4096, 256, 0, stream>>>(dWhh1, U(O_DW1HHI), U(O_DW1HLO), 1024, 10);
    pack_bias_kernel<<<16, 256, 0, stream>>>(ebih0, ebhh0, ebih1, ebhh1, dbih0, dbhh0, dbih1, dbhh1,
                                             F(O_BIAS), F(O_BIAS + 16384), F(O_BIAS + 32768), F(O_BIAS + 49152));
    prep_misc<<<1024, 256, 0, stream>>>(src, trg,
                                        U(O_H0THI_A), U(O_H0TLO_A), U(O_H1THI_A), U(O_H1TLO_A),
                                        F(O_C0), F(O_C1),
                                        U(O_SXHI), U(O_SXLO), U(O_EXHI), U(O_EXLO),
                                        U(O_XBHI), U(O_XBLO));

    unsigned short *h0ih = U(O_H0THI_A), *h0il = U(O_H0TLO_A);
    unsigned short *h0oh = U(O_H0THI_B), *h0ol = U(O_H0TLO_B);
    unsigned short *h1ih = U(O_H1THI_A), *h1il = U(O_H1TLO_A);
    unsigned short *h1oh = U(O_H1THI_B), *h1ol = U(O_H1TLO_B);
    float* c0 = F(O_C0);
    float* c1 = F(O_C1);
    float* h0km = F(O_H0KM);
    float* h1km = F(O_H1KM);

    // ---- encoder ----
    for (int t = 0; t < LIN; t++) {
        lstm_phase_mfma<1, 64, 64><<<64, 1024, 0, stream>>>(
            U(O_SXHI) + t * 4096, U(O_SXLO) + t * 4096, h0ih, h0il,
            U(O_EW0XHI), U(O_EW0XLO), U(O_EW0HHI), U(O_EW0HLO),
            F(O_BIAS), c0, h0oh, h0ol, h0km);
        lstm_phase_mfma<8, 128, 1024><<<64, 1024, 0, stream>>>(
            h0oh, h0ol, h1ih, h1il,
            U(O_EW1XHI), U(O_EW1XLO), U(O_EW1HHI), U(O_EW1HLO),
            F(O_BIAS + 16384), c1, h1oh, h1ol, h1km);
        unsigned short* tp;
        tp = h0ih; h0ih = h0oh; h0oh = tp;
        tp = h0il; h0il = h0ol; h0ol = tp;
        tp = h1ih; h1ih = h1oh; h1oh = tp;
        tp = h1il; h1il = h1ol; h1ol = tp;
    }

    // ---- decoder ----
    for (int t = 0; t < LOUT; t++) {
        lstm_phase_mfma<1, 64, 64><<<64, 1024, 0, stream>>>(
            U(O_XBHI), U(O_XBLO), h0ih, h0il,
            U(O_DW0XHI), U(O_DW0XLO), U(O_DW0HHI), U(O_DW0HLO),
            F(O_BIAS + 32768), c0, h0oh, h0ol, h0km);
        lstm_phase_mfma<8, 128, 1024><<<64, 1024, 0, stream>>>(
            h0oh, h0ol, h1ih, h1il,
            U(O_DW1XHI), U(O_DW1XLO), U(O_DW1HHI), U(O_DW1HLO),
            F(O_BIAS + 49152), c1, h1oh, h1ol, h1km);
        fc_kernel<<<64, 256, 0, stream>>>(h1km, fcW, fcb, U(O_EXHI), U(O_EXLO),
                                          U(O_XBHI), U(O_XBLO), out, t);
        unsigned short* tp;
        tp = h0ih; h0ih = h0oh; h0oh = tp;
        tp = h0il; h0il = h0ol; h0ol = tp;
        tp = h1ih; h1ih = h1oh; h1oh = tp;
        tp = h1il; h1il = h1ol; h1ol = tp;
    }
}

// Round 3
// 8652.222 us; speedup vs baseline: 9.2760x; 3.9484x over previous
//
#include <hip/hip_runtime.h>
#include <math.h>

#define LIN 256
#define LOUT 64
#define NENDO 48

typedef __attribute__((ext_vector_type(8))) short short8;
typedef __attribute__((ext_vector_type(4))) float f32x4;

// ---------------- ws layout (bytes) ----------------
// A-packs: [256 tiles][NC chunks][2 splits][512 shorts]  (NC: L0-type=34, L1-type=64)
constexpr size_t O_APE0 = 0;
constexpr size_t O_APE1 = O_APE0 + (size_t)256 * 34 * 1024 * 2;
constexpr size_t O_APD0 = O_APE1 + (size_t)256 * 64 * 1024 * 2;
constexpr size_t O_APD1 = O_APD0 + (size_t)256 * 34 * 1024 * 2;
constexpr size_t O_SXHI = O_APD1 + (size_t)256 * 64 * 1024 * 2;  // [256 t][64 b][64 k]
constexpr size_t O_SXLO = O_SXHI + 2097152;
constexpr size_t O_EXHI = O_SXLO + 2097152;                      // [64 t][64 b][16 e]
constexpr size_t O_EXLO = O_EXHI + 131072;
constexpr size_t O_H0   = O_EXLO + 131072;                       // 4 x 131072: [pp][hi/lo] [64 b][1024 k]
constexpr size_t O_H1   = O_H0 + 4 * 131072;
constexpr size_t O_C0   = O_H1 + 4 * 131072;                     // fp32 [1024][64]
constexpr size_t O_C1   = O_C0 + 262144;
constexpr size_t O_KMS  = O_C1 + 262144;                         // sink [1024][64]
constexpr size_t O_H1KM = O_KMS + 262144;                        // fp32 [1024][64] for fc
constexpr size_t O_XBHI = O_H1KM + 262144;                       // [64 b][64 k]
constexpr size_t O_XBLO = O_XBHI + 8192;
constexpr size_t O_BIAS = O_XBLO + 8192;                         // 4 x [1024][4] fp32
// total ~109.4 MB (== round-1's proven footprint)

__device__ __forceinline__ unsigned short f2bh(float x) {
    unsigned int u = __float_as_uint(x);
    unsigned int r = (u + 0x7fffu + ((u >> 16) & 1u)) >> 16;
    return (unsigned short)r;
}
__device__ __forceinline__ float bh2f(unsigned short h) {
    return __uint_as_float(((unsigned int)h) << 16);
}
__device__ __forceinline__ float sigf(float x) { return 1.0f / (1.0f + expf(-x)); }

// ---------------- A pre-pack into MFMA fragment order ----------------
// out[tile][chunk][split][lane*8+e]; tile row p = T*16 + (lane&15), k = chunk*32 + (lane>>4)*8 + e
// source row (packed p = hcol*4+gate) comes from W[gate*1024+hcol][...]; k<KX from Wx else Wh[k-KX]
__global__ void pack_apack(const float* __restrict__ Wx, const float* __restrict__ Wh,
                           unsigned short* __restrict__ out, int KX, int NC)
{
    const int n = 256 * NC * 512;
    for (int j = blockIdx.x * blockDim.x + threadIdx.x; j < n; j += gridDim.x * blockDim.x) {
        int r2 = j & 511;
        int c = (j >> 9) % NC;
        int T = (j >> 9) / NC;
        int l = r2 >> 3, e = r2 & 7;
        int l15 = l & 15, lq = l >> 4;
        int p = T * 16 + l15;
        int hcol = p >> 2, gate = p & 3;
        int k = c * 32 + lq * 8 + e;
        float v = (k < KX) ? Wx[(gate * 1024 + hcol) * KX + k]
                           : Wh[(gate * 1024 + hcol) * 1024 + (k - KX)];
        unsigned short h = f2bh(v);
        size_t o = ((size_t)(T * NC + c) * 2) * 512 + r2;
        out[o] = h;
        out[o + 512] = f2bh(v - bh2f(h));
    }
}

__global__ void pack_bias_kernel(const float* a0, const float* b0, const float* a1, const float* b1,
                                 const float* a2, const float* b2, const float* a3, const float* b3,
                                 float* d0, float* d1, float* d2, float* d3)
{
    int i = blockIdx.x * blockDim.x + threadIdx.x;
    if (i >= 4096) return;
    int hcol = i >> 2, gate = i & 3, s = (gate << 10) + hcol;
    d0[i] = a0[s] + b0[s];
    d1[i] = a1[s] + b1[s];
    d2[i] = a2[s] + b2[s];
    d3[i] = a3[s] + b3[s];
}

// ---------------- misc prep ----------------
__global__ void prep_misc(const float* __restrict__ src, const float* __restrict__ trg,
                          unsigned short* __restrict__ hz,      // 8 x 65536 at O_H0
                          float* __restrict__ c0, float* __restrict__ c1,
                          unsigned short* sxhi, unsigned short* sxlo,
                          unsigned short* exhi, unsigned short* exlo,
                          unsigned short* xbhi, unsigned short* xblo)
{
    const int N0 = 524288, N1 = 131072, N2 = 1048576, N3 = 65536, N4 = 4096;
    const int TOT = N0 + N1 + N2 + N3 + N4;
    for (int i = blockIdx.x * blockDim.x + threadIdx.x; i < TOT; i += gridDim.x * blockDim.x) {
        if (i < N0) {
            hz[i] = 0;
        } else if (i < N0 + N1) {
            int j = i - N0;
            if (j < 65536) c0[j] = 0.0f; else c1[j - 65536] = 0.0f;
        } else if (i < N0 + N1 + N2) {
            int j = i - (N0 + N1);
            int t = j >> 12, b = (j >> 6) & 63, k = j & 63;
            float v = src[(b * LIN + t) * 64 + k];
            unsigned short h = f2bh(v);
            sxhi[j] = h; sxlo[j] = f2bh(v - bh2f(h));
        } else if (i < N0 + N1 + N2 + N3) {
            int j = i - (N0 + N1 + N2);
            int t = j >> 10, b = (j >> 4) & 63, e = j & 15;
            float v = trg[(b * LOUT + t) * 64 + NENDO + e];
            unsigned short h = f2bh(v);
            exhi[j] = h; exlo[j] = f2bh(v - bh2f(h));
        } else {
            int j = i - (N0 + N1 + N2 + N3);
            int b = j >> 6, k = j & 63;
            float v = src[(b * LIN + (LIN - 1)) * 64 + k];
            unsigned short h = f2bh(v);
            xbhi[j] = h; xblo[j] = f2bh(v - bh2f(h));
        }
    }
}

// ---------------- LSTM phase core ----------------
// 512 threads = 8 waves (2 row-tiles x 4 batch-tiles). Block owns 32 packed rows (8 hcols) x 64 batch.
// B (states, [64][stride] bf16 hi/lo) staged per 128-k buffer in XOR-swizzled LDS, double-buffered.
// A read coalesced from fragment-packed ws. 3-MFMA split-bf16 accumulate (hi*hi + hi*lo + lo*hi).
template <int NBUF, int XB, int B0S>
__device__ __forceinline__ void phase_core(
    const int rowbase, const int tid, unsigned short* lds,
    const unsigned short* __restrict__ xhi, const unsigned short* __restrict__ xlo, const int xs,
    const unsigned short* __restrict__ hhi, const unsigned short* __restrict__ hlo,
    const unsigned short* __restrict__ ap,
    const float* __restrict__ biasP,
    float* __restrict__ cst,
    unsigned short* __restrict__ hohi, unsigned short* __restrict__ holo,
    float* __restrict__ hkm)
{
    constexpr int NC = B0S + (NBUF - 1) * 4;
    const int l = tid & 63;
    const int w = tid >> 6;
    const int rt = w >> 2, bt = w & 3;
    const int l15 = l & 15, lq = l >> 4;

    f32x4 acc = {0.f, 0.f, 0.f, 0.f};
    short8 v0h, v0l, v1h, v1l;

    auto do_load = [&](int ib) {
        const unsigned short *ph, *pl; int bs, kb;
        if (ib < XB) { ph = xhi; pl = xlo; bs = xs; kb = ib * 128; }
        else { ph = hhi; pl = hlo; bs = 1024; kb = (ib - XB) * 128; }
        if (B0S == 2 && ib == 0) {
            int row = tid >> 3, kk = (tid & 7) * 8;
            v0h = *(const short8*)(ph + row * bs + kk);
            v0l = *(const short8*)(pl + row * bs + kk);
        } else {
            int row = tid >> 4, kk = (tid & 15) * 8;
            v0h = *(const short8*)(ph + row * bs + kb + kk);
            v1h = *(const short8*)(ph + (row + 32) * bs + kb + kk);
            v0l = *(const short8*)(pl + row * bs + kb + kk);
            v1l = *(const short8*)(pl + (row + 32) * bs + kb + kk);
        }
    };
    auto do_write = [&](int ib, int pb) {
        unsigned short* d0 = lds + pb * 16384;
        unsigned short* d1 = d0 + 8192;
        if (B0S == 2 && ib == 0) {
            int row = tid >> 3, kk = (tid & 7) * 8;
            int ix = (row * 128 + kk) ^ ((row & 7) << 3);
            *(short8*)(d0 + ix) = v0h;
            *(short8*)(d1 + ix) = v0l;
        } else {
            int row = tid >> 4, kk = (tid & 15) * 8;
            int i0 = (row * 128 + kk) ^ ((row & 7) << 3);
            int i1 = ((row + 32) * 128 + kk) ^ ((row & 7) << 3);
            *(short8*)(d0 + i0) = v0h;
            *(short8*)(d0 + i1) = v1h;
            *(short8*)(d1 + i0) = v0l;
            *(short8*)(d1 + i1) = v1l;
        }
    };
    auto compute = [&](int ib, int pb) {
        const int cg0 = (ib == 0) ? 0 : B0S + (ib - 1) * 4;
        const int ns = (ib == 0) ? B0S : 4;
        const unsigned short* ab = ap + ((size_t)((rowbase >> 4) + rt) * NC + cg0) * 1024 + l * 8;
        const unsigned short* s0 = lds + pb * 16384;
        const unsigned short* s1 = s0 + 8192;
#pragma unroll 4
        for (int s = 0; s < ns; s++) {
            short8 ah = *(const short8*)(ab + s * 1024);
            short8 al = *(const short8*)(ab + s * 1024 + 512);
            int bi = ((16 * bt + l15) * 128 + s * 32 + lq * 8) ^ ((l15 & 7) << 3);
            short8 bh = *(const short8*)(s0 + bi);
            short8 bl = *(const short8*)(s1 + bi);
            acc = __builtin_amdgcn_mfma_f32_16x16x32_bf16(ah, bh, acc, 0, 0, 0);
            acc = __builtin_amdgcn_mfma_f32_16x16x32_bf16(ah, bl, acc, 0, 0, 0);
            acc = __builtin_amdgcn_mfma_f32_16x16x32_bf16(al, bh, acc, 0, 0, 0);
        }
    };

    do_load(0);
    do_write(0, 0);
    __syncthreads();
    for (int ib = 0; ib < NBUF; ib++) {
        if (ib + 1 < NBUF) do_load(ib + 1);           // issue next-buffer loads early (T14)
        compute(ib, ib & 1);
        if (ib + 1 < NBUF) do_write(ib + 1, (ib + 1) & 1);
        __syncthreads();
    }

    // ---- epilogue: lane holds gates i,f,g,o (acc[0..3]) for (hcol, b) ----
    const int hcol = (rowbase >> 2) + rt * 4 + lq;
    const int b = 16 * bt + l15;
    const f32x4 bias = *(const f32x4*)(biasP + hcol * 4);
    float ig = sigf(acc[0] + bias[0]);
    float fg = sigf(acc[1] + bias[1]);
    float gv = tanhf(acc[2] + bias[2]);
    float og = sigf(acc[3] + bias[3]);
    const int ci = hcol * 64 + b;
    float cv = fg * cst[ci] + ig * gv;
    cst[ci] = cv;
    float hv = og * tanhf(cv);
    hkm[ci] = hv;
    unsigned short hh = f2bh(hv);
    hohi[b * 1024 + hcol] = hh;
    holo[b * 1024 + hcol] = f2bh(hv - bh2f(hh));
}

// ---------------- fused encoder pair: blocks 0-127 = L0(t), 128-255 = L1(t-1) ----------------
__global__ __launch_bounds__(512) void enc_pair_kernel(
    int runL0, int runL1,
    const unsigned short* sxh, const unsigned short* sxl,
    const unsigned short* h0ih, const unsigned short* h0il,
    unsigned short* h0oh, unsigned short* h0ol,
    const unsigned short* h1ih, const unsigned short* h1il,
    unsigned short* h1oh, unsigned short* h1ol,
    const unsigned short* ap0, const unsigned short* ap1,
    const float* bias0, const float* bias1,
    float* c0, float* c1, float* kms)
{
    __shared__ unsigned short lds[32768];
    if (blockIdx.x < 128) {
        if (!runL0) return;
        phase_core<9, 1, 2>(blockIdx.x * 32, threadIdx.x, lds, sxh, sxl, 64,
                            h0ih, h0il, ap0, bias0, c0, h0oh, h0ol, kms);
    } else {
        if (!runL1) return;
        phase_core<16, 8, 4>((blockIdx.x - 128) * 32, threadIdx.x, lds, h0ih, h0il, 1024,
                             h1ih, h1il, ap1, bias1, c1, h1oh, h1ol, kms);
    }
}

__global__ __launch_bounds__(512) void dec_phase0_kernel(
    const unsigned short* xbh, const unsigned short* xbl,
    const unsigned short* h0ih, const unsigned short* h0il,
    unsigned short* h0oh, unsigned short* h0ol,
    const unsigned short* ap, const float* bias, float* c0, float* kms)
{
    __shared__ unsigned short lds[32768];
    phase_core<9, 1, 2>(blockIdx.x * 32, threadIdx.x, lds, xbh, xbl, 64,
                        h0ih, h0il, ap, bias, c0, h0oh, h0ol, kms);
}

__global__ __launch_bounds__(512) void dec_phase1_kernel(
    const unsigned short* xh, const unsigned short* xl,
    const unsigned short* h1ih, const unsigned short* h1il,
    unsigned short* h1oh, unsigned short* h1ol,
    const unsigned short* ap, const float* bias, float* c1, float* km)
{
    __shared__ unsigned short lds[32768];
    phase_core<16, 8, 4>(blockIdx.x * 32, threadIdx.x, lds, xh, xl, 1024,
                         h1ih, h1il, ap, bias, c1, h1oh, h1ol, km);
}

// ---------------- decoder fc + next-x assembly ----------------
__global__ __launch_bounds__(256) void fc_kernel(
    const float* __restrict__ h1, const float* __restrict__ fcW, const float* __restrict__ fcb,
    const unsigned short* __restrict__ exhi, const unsigned short* __restrict__ exlo,
    unsigned short* __restrict__ xbhi, unsigned short* __restrict__ xblo,
    float* __restrict__ out, int t)
{
    const int tid = threadIdx.x, lane = tid & 63;
    const int w = __builtin_amdgcn_readfirstlane(tid >> 6);
    const int blk = blockIdx.x;
    if (blk < NENDO) {
        float acc = 0.0f;
        const int ks = 256 * w, ke = ks + 256;
#pragma unroll 4
        for (int k = ks; k < ke; k++)
            acc = fmaf(h1[k * 64 + lane], fcW[blk * 1024 + k], acc);
        __shared__ float red[4][64];
        red[w][lane] = acc;
        __syncthreads();
        if (tid < 64) {
            float s = fcb[blk] + red[0][lane] + red[1][lane] + red[2][lane] + red[3][lane];
            out[lane * (LOUT * NENDO) + t * NENDO + blk] = s;
            unsigned short h = f2bh(s);
            xbhi[lane * 64 + blk] = h;
            xblo[lane * 64 + blk] = f2bh(s - bh2f(h));
        }
    } else {
        int e = blk - NENDO;
        if (tid < 64) {
            int si = t * 1024 + lane * 16 + e;
            xbhi[lane * 64 + NENDO + e] = exhi[si];
            xblo[lane * 64 + NENDO + e] = exlo[si];
        }
    }
}

extern "C" void kernel_launch(void* const* d_in, const int* in_sizes, int n_in,
                              void* d_out, int out_size, void* d_ws, size_t ws_size,
                              hipStream_t stream)
{
    const float* src = (const float*)d_in[0];
    const float* trg = (const float*)d_in[1];
    const float* eWih0 = (const float*)d_in[2];
    const float* eWhh0 = (const float*)d_in[3];
    const float* ebih0 = (const float*)d_in[4];
    const float* ebhh0 = (const float*)d_in[5];
    const float* eWih1 = (const float*)d_in[6];
    const float* eWhh1 = (const float*)d_in[7];
    const float* ebih1 = (const float*)d_in[8];
    const float* ebhh1 = (const float*)d_in[9];
    const float* dWih0 = (const float*)d_in[10];
    const float* dWhh0 = (const float*)d_in[11];
    const float* dbih0 = (const float*)d_in[12];
    const float* dbhh0 = (const float*)d_in[13];
    const float* dWih1 = (const float*)d_in[14];
    const float* dWhh1 = (const float*)d_in[15];
    const float* dbih1 = (const float*)d_in[16];
    const float* dbhh1 = (const float*)d_in[17];
    const float* fcW = (const float*)d_in[18];
    const float* fcb = (const float*)d_in[19];

    char* wsb = (char*)d_ws;
    float* out = (float*)d_out;
    auto U = [&](size_t o) { return (unsigned short*)(wsb + o); };
    auto F = [&](size_t o) { return (float*)(wsb + o); };

    // ---- prep ----
    pack_apack<<<2048, 256, 0, stream>>>(eWih0, eWhh0, U(O_APE0), 64, 34);
    pack_apack<<<4096, 256, 0, stream>>>(eWih1, eWhh1, U(O_APE1), 1024, 64);
    pack_apack<<<2048, 256, 0, stream>>>(dWih0, dWhh0, U(O_APD0), 64, 34);
    pack_apack<<<4096, 256, 0, stream>>>(dWih1, dWhh1, U(O_APD1), 1024, 64);
    pack_bias_kernel<<<16, 256, 0, stream>>>(ebih0, ebhh0, ebih1, ebhh1, dbih0, dbhh0, dbih1, dbhh1,
                                             F(O_BIAS), F(O_BIAS + 16384), F(O_BIAS + 32768), F(O_BIAS + 49152));
    prep_misc<<<1024, 256, 0, stream>>>(src, trg, U(O_H0), F(O_C0), F(O_C1),
                                        U(O_SXHI), U(O_SXLO), U(O_EXHI), U(O_EXLO),
                                        U(O_XBHI), U(O_XBLO));

    // state buffers: h0 ping-pong p: hi @ O_H0 + (p*2)*131072, lo @ +131072
    unsigned short* h0hi[2] = { U(O_H0), U(O_H0 + 2 * 131072) };
    unsigned short* h0lo[2] = { U(O_H0 + 131072), U(O_H0 + 3 * 131072) };
    unsigned short* h1hi[2] = { U(O_H1), U(O_H1 + 2 * 131072) };
    unsigned short* h1lo[2] = { U(O_H1 + 131072), U(O_H1 + 3 * 131072) };
    float* c0 = F(O_C0);
    float* c1 = F(O_C1);
    float* kms = F(O_KMS);
    float* h1km = F(O_H1KM);

    // ---- encoder: 257 fused dispatches; dispatch d runs L0(step d) and L1(step d-1) ----
    for (int d = 0; d <= LIN; d++) {
        int pi = d & 1, po = (d + 1) & 1;
        enc_pair_kernel<<<256, 512, 0, stream>>>(
            d < LIN ? 1 : 0, d >= 1 ? 1 : 0,
            U(O_SXHI) + (size_t)d * 4096, U(O_SXLO) + (size_t)d * 4096,
            h0hi[pi], h0lo[pi], h0hi[po], h0lo[po],
            h1hi[pi], h1lo[pi], h1hi[po], h1lo[po],
            U(O_APE0), U(O_APE1), F(O_BIAS), F(O_BIAS + 16384),
            c0, c1, kms);
    }
    // after loop: h0 final in buf[0], h1 final in buf[1]
    int p0 = 0, p1 = 1;

    // ---- decoder ----
    for (int t = 0; t < LOUT; t++) {
        dec_phase0_kernel<<<128, 512, 0, stream>>>(
            U(O_XBHI), U(O_XBLO), h0hi[p0], h0lo[p0], h0hi[p0 ^ 1], h0lo[p0 ^ 1],
            U(O_APD0), F(O_BIAS + 32768), c0, kms);
        dec_phase1_kernel<<<128, 512, 0, stream>>>(
            h0hi[p0 ^ 1], h0lo[p0 ^ 1], h1hi[p1], h1lo[p1], h1hi[p1 ^ 1], h1lo[p1 ^ 1],
            U(O_APD1), F(O_BIAS + 49152), c1, h1km);
        fc_kernel<<<64, 256, 0, stream>>>(h1km, fcW, fcb, U(O_EXHI), U(O_EXLO),
                                          U(O_XBHI), U(O_XBLO), out, t);
        p0 ^= 1; p1 ^= 1;
    }
}